// Round 6
// baseline (644.358 us; speedup 1.0000x reference)
//
#include <hip/hip_runtime.h>
#include <hip/hip_cooperative_groups.h>
namespace cg = cooperative_groups;

#define TOK   65536
#define HID   768
#define NSEQ  128
#define FFD   3072
#define GRID  512
#define CHUNK 128              // tokens per pool block (TOK / GRID)
#define RMAX  6                // max runs per 128-token chunk (seg len >= 32 proven)
#define KCH   96               // k per gemm split (6 iters of k16)
#define KS1   8                // 8*96 = 768
#define KS2   32               // 32*96 = 3072

__device__ __forceinline__ void add4(float4& a, const float4 b) {
  a.x += b.x; a.y += b.y; a.z += b.z; a.w += b.w;
}

__device__ __forceinline__ void scan_lens(const int* __restrict__ lens,
                                          int* sc, int tid) {
  if (tid < NSEQ) sc[tid] = lens[tid];
  __syncthreads();
  for (int off = 1; off < NSEQ; off <<= 1) {   // Hillis-Steele inclusive scan
    int v = 0;
    if (tid < NSEQ && tid >= off) v = sc[tid - off];
    __syncthreads();
    if (tid < NSEQ) sc[tid] += v;
    __syncthreads();
  }
}

// P1: pool 128-token chunk b into per-run partial sums (no atomics).
__device__ __forceinline__ void pool_phase(const float* __restrict__ x,
                                           const int* sc,
                                           float* __restrict__ partial,
                                           int b, int tid) {
  if (tid >= 192) return;
  const int t0 = b * CHUNK;
  const int t1 = t0 + CHUNK;
  int lo = 0, hi = NSEQ - 1;                   // first seg with incl > t0
  while (lo < hi) { int m = (lo + hi) >> 1; if (sc[m] <= t0) lo = m + 1; else hi = m; }
  int seg = lo;
  int segend = sc[seg];
  const float4* xv = (const float4*)x + (size_t)t0 * (HID / 4) + tid;
  int t = t0, ridx = 0;
  while (t < t1 && ridx < RMAX) {
    const int run_end = segend < t1 ? segend : t1;
    const int n = run_end - t;
    const float4* p = xv + (size_t)(t - t0) * (HID / 4);
    float4 a0 = make_float4(0.f,0.f,0.f,0.f), a1 = a0, a2 = a0, a3 = a0,
           a4 = a0, a5 = a0, a6 = a0, a7 = a0;
    int i = 0;
    for (; i + 8 <= n; i += 8) {               // 8 independent loads in flight
      add4(a0, p[(size_t)(i+0) * 192]); add4(a1, p[(size_t)(i+1) * 192]);
      add4(a2, p[(size_t)(i+2) * 192]); add4(a3, p[(size_t)(i+3) * 192]);
      add4(a4, p[(size_t)(i+4) * 192]); add4(a5, p[(size_t)(i+5) * 192]);
      add4(a6, p[(size_t)(i+6) * 192]); add4(a7, p[(size_t)(i+7) * 192]);
    }
    for (; i < n; ++i) add4(a0, p[(size_t)i * 192]);
    add4(a0, a1); add4(a2, a3); add4(a4, a5); add4(a6, a7);
    add4(a0, a2); add4(a4, a6); add4(a0, a4);
    ((float4*)(partial + ((size_t)b * RMAX + ridx) * HID))[tid] = a0;
    ++ridx;
    t = run_end;
    if (run_end == segend) { ++seg; if (seg < NSEQ) segend = sc[seg]; }
  }
}

// P2: per-segment reduce of run partials -> pooled (scaled by 1/L).
__device__ __forceinline__ void segreduce_phase(const float* __restrict__ partial,
                                                const int* sc,
                                                float* __restrict__ pooled,
                                                int b, int tid) {
  if (b >= NSEQ || tid >= 192) return;
  const int s = b;
  const int sstart = s ? sc[s - 1] : 0;
  const int send = sc[s];
  const int c0 = sstart >> 7, c1 = (send - 1) >> 7;
  float4 acc = make_float4(0.f, 0.f, 0.f, 0.f);
  for (int c = c0; c <= c1; ++c) {
    const int t0c = c << 7;
    int lo = 0, hi = NSEQ - 1;                 // start_seg(chunk c)
    while (lo < hi) { int m = (lo + hi) >> 1; if (sc[m] <= t0c) lo = m + 1; else hi = m; }
    const int r = s - lo;
    if (r >= 0 && r < RMAX)
      add4(acc, ((const float4*)(partial + ((size_t)c * RMAX + r) * HID))[tid]);
  }
  const float inv = 1.0f / (float)(send - sstart);
  acc.x *= inv; acc.y *= inv; acc.z *= inv; acc.w *= inv;
  ((float4*)(pooled + (size_t)s * HID))[tid] = acc;
}

// One 128s x 64f tile of C = A[128 x Kt] * B[N x Kt]^T over [k0, k0+KCH).
// 256 threads, thread tile 8s x 4f.
__device__ __forceinline__ void gemm_tile(
    const float* __restrict__ A, const float* __restrict__ B,
    float* __restrict__ C, int N, int Kt, int f0, int k0, int tid) {
  __shared__ float As[16][132];   // [k][s]; pad -> 2-way max bank alias (free)
  __shared__ float Bs[16][68];    // [k][f]
  const int fx = (tid & 15) * 4;
  const int sy = (tid >> 4) * 8;

  float acc[8][4];
  #pragma unroll
  for (int i = 0; i < 8; ++i)
    #pragma unroll
    for (int j = 0; j < 4; ++j) acc[i][j] = 0.f;

  for (int kc = k0; kc < k0 + KCH; kc += 16) {
    #pragma unroll
    for (int r = 0; r < 2; ++r) {             // stage A: 128x16 via float4-of-k
      const int l = tid + 256 * r;
      const int s = l >> 2, k4 = (l & 3) * 4;
      const float4 v = *(const float4*)(A + (size_t)s * Kt + kc + k4);
      As[k4 + 0][s] = v.x; As[k4 + 1][s] = v.y;
      As[k4 + 2][s] = v.z; As[k4 + 3][s] = v.w;
    }
    {                                         // stage B: 64x16 via float4-of-k
      const int f = tid >> 2, k4 = (tid & 3) * 4;
      const float4 v = *(const float4*)(B + (size_t)(f0 + f) * Kt + kc + k4);
      Bs[k4 + 0][f] = v.x; Bs[k4 + 1][f] = v.y;
      Bs[k4 + 2][f] = v.z; Bs[k4 + 3][f] = v.w;
    }
    __syncthreads();
    #pragma unroll
    for (int kk = 0; kk < 16; ++kk) {
      const float4 aA = *(const float4*)&As[kk][sy];
      const float4 aB = *(const float4*)&As[kk][sy + 4];
      const float4 bb = *(const float4*)&Bs[kk][fx];
      acc[0][0] += aA.x*bb.x; acc[0][1] += aA.x*bb.y; acc[0][2] += aA.x*bb.z; acc[0][3] += aA.x*bb.w;
      acc[1][0] += aA.y*bb.x; acc[1][1] += aA.y*bb.y; acc[1][2] += aA.y*bb.z; acc[1][3] += aA.y*bb.w;
      acc[2][0] += aA.z*bb.x; acc[2][1] += aA.z*bb.y; acc[2][2] += aA.z*bb.z; acc[2][3] += aA.z*bb.w;
      acc[3][0] += aA.w*bb.x; acc[3][1] += aA.w*bb.y; acc[3][2] += aA.w*bb.z; acc[3][3] += aA.w*bb.w;
      acc[4][0] += aB.x*bb.x; acc[4][1] += aB.x*bb.y; acc[4][2] += aB.x*bb.z; acc[4][3] += aB.x*bb.w;
      acc[5][0] += aB.y*bb.x; acc[5][1] += aB.y*bb.y; acc[5][2] += aB.y*bb.z; acc[5][3] += aB.y*bb.w;
      acc[6][0] += aB.z*bb.x; acc[6][1] += aB.z*bb.y; acc[6][2] += aB.z*bb.z; acc[6][3] += aB.z*bb.w;
      acc[7][0] += aB.w*bb.x; acc[7][1] += aB.w*bb.y; acc[7][2] += aB.w*bb.z; acc[7][3] += aB.w*bb.w;
    }
    __syncthreads();
  }
  #pragma unroll
  for (int i = 0; i < 8; ++i)
    *(float4*)(C + (size_t)(sy + i) * N + f0 + fx) =
        make_float4(acc[i][0], acc[i][1], acc[i][2], acc[i][3]);
}

// P4: h1 = sum of the KS1 gemm1 partial slabs (one float4 per thread).
__device__ __forceinline__ void reduceh1_phase(const float* __restrict__ h1p,
                                               float* __restrict__ h1, size_t i) {
  if (i >= (size_t)NSEQ * FFD / 4) return;
  const float4* src = (const float4*)h1p;
  float4 a = src[i];
  #pragma unroll
  for (int p = 1; p < KS1; ++p) add4(a, src[i + (size_t)p * (NSEQ * FFD / 4)]);
  ((float4*)h1)[i] = a;
}

// P6: fold KS2 gemm2 slabs + L2 normalize row s.
__device__ __forceinline__ void norm_phase(const float* __restrict__ outp,
                                           float* __restrict__ out, int s, int tid) {
  __shared__ float wsum[4];
  float v[3];
  #pragma unroll
  for (int j = 0; j < 3; ++j) {
    const int c = tid + 256 * j;
    float a = 0.f;
    for (int p = 0; p < KS2; ++p) a += outp[((size_t)p * NSEQ + s) * HID + c];
    v[j] = a;
  }
  float ss = v[0]*v[0] + v[1]*v[1] + v[2]*v[2];
  #pragma unroll
  for (int off = 32; off > 0; off >>= 1) ss += __shfl_down(ss, off, 64);
  if ((tid & 63) == 0) wsum[tid >> 6] = ss;
  __syncthreads();
  const float tot = wsum[0] + wsum[1] + wsum[2] + wsum[3];
  const float scale = 1.0f / fmaxf(sqrtf(tot), 1e-12f);
  #pragma unroll
  for (int j = 0; j < 3; ++j) out[(size_t)s * HID + tid + 256 * j] = v[j] * scale;
}

// ---------------- cooperative mega-kernel (512 blocks, 2/CU: big margin) ----
__global__ __launch_bounds__(256, 2) void mega_kernel(
    const float* __restrict__ x, const int* __restrict__ lens,
    const float* __restrict__ W1, const float* __restrict__ W2,
    float* __restrict__ out, float* __restrict__ pooled,
    float* __restrict__ partial, float* __restrict__ h1p,
    float* __restrict__ h1, float* __restrict__ outp) {
  cg::grid_group grid = cg::this_grid();
  const int tid = threadIdx.x;
  const int b = blockIdx.x;
  __shared__ int sc[NSEQ];

  scan_lens(lens, sc, tid);
  pool_phase(x, sc, partial, b, tid);
  grid.sync();
  segreduce_phase(partial, sc, pooled, b, tid);
  grid.sync();
  if (b < 48 * KS1)
    gemm_tile(pooled, W1, h1p + (size_t)(b / 48) * NSEQ * FFD,
              FFD, HID, (b % 48) * 64, (b / 48) * KCH, tid);
  grid.sync();
  reduceh1_phase(h1p, h1, (size_t)b * 256 + tid);
  grid.sync();
  if (b < 12 * KS2)
    gemm_tile(h1, W2, outp + (size_t)(b / 12) * NSEQ * HID,
              HID, FFD, (b % 12) * 64, (b / 12) * KCH, tid);
  grid.sync();
  if (b < NSEQ) norm_phase(outp, out, b, tid);
}

// ---------------- non-cooperative fallback chain ----------------------------
__global__ __launch_bounds__(256) void k_pool(const float* __restrict__ x,
                                              const int* __restrict__ lens,
                                              float* __restrict__ partial) {
  __shared__ int sc[NSEQ];
  scan_lens(lens, sc, threadIdx.x);
  pool_phase(x, sc, partial, blockIdx.x, threadIdx.x);
}
__global__ __launch_bounds__(256) void k_segred(const float* __restrict__ partial,
                                                const int* __restrict__ lens,
                                                float* __restrict__ pooled) {
  __shared__ int sc[NSEQ];
  scan_lens(lens, sc, threadIdx.x);
  segreduce_phase(partial, sc, pooled, blockIdx.x, threadIdx.x);
}
__global__ __launch_bounds__(256) void k_gemm1(const float* __restrict__ pooled,
                                               const float* __restrict__ W1,
                                               float* __restrict__ h1p) {
  const int b = blockIdx.x;
  gemm_tile(pooled, W1, h1p + (size_t)(b / 48) * NSEQ * FFD,
            FFD, HID, (b % 48) * 64, (b / 48) * KCH, threadIdx.x);
}
__global__ __launch_bounds__(256) void k_redh1(const float* __restrict__ h1p,
                                               float* __restrict__ h1) {
  reduceh1_phase(h1p, h1, (size_t)blockIdx.x * 256 + threadIdx.x);
}
__global__ __launch_bounds__(256) void k_gemm2(const float* __restrict__ h1,
                                               const float* __restrict__ W2,
                                               float* __restrict__ outp) {
  const int b = blockIdx.x;
  gemm_tile(h1, W2, outp + (size_t)(b / 12) * NSEQ * HID,
            HID, FFD, (b % 12) * 64, (b / 12) * KCH, threadIdx.x);
}
__global__ __launch_bounds__(256) void k_norm(const float* __restrict__ outp,
                                              float* __restrict__ out) {
  norm_phase(outp, out, blockIdx.x, threadIdx.x);
}

extern "C" void kernel_launch(void* const* d_in, const int* in_sizes, int n_in,
                              void* d_out, int out_size, void* d_ws, size_t ws_size,
                              hipStream_t stream) {
  const float* x    = (const float*)d_in[0];  // [65536, 768]
  const int*   lens = (const int*)d_in[1];    // [128]
  const float* W1   = (const float*)d_in[2];  // [3072, 768]
  const float* W2   = (const float*)d_in[3];  // [768, 3072]
  float* out = (float*)d_out;                 // [128, 768]

  float* pooled  = (float*)d_ws;                         // 128*768
  float* partial = pooled + NSEQ * HID;                  // 512*6*768
  float* h1p     = partial + (size_t)GRID * RMAX * HID;  // 8*128*3072
  float* h1      = h1p + (size_t)KS1 * NSEQ * FFD;       // 128*3072
  float* outp    = h1 + NSEQ * FFD;                      // 32*128*768

  // Deterministic host-side capacity check (capture-safe pure query).
  int maxb = 0;
  hipOccupancyMaxActiveBlocksPerMultiprocessor(&maxb, (const void*)mega_kernel, 256, 0);
  if (maxb >= 2) {
    void* args[] = {(void*)&x, (void*)&lens, (void*)&W1, (void*)&W2,
                    (void*)&out, (void*)&pooled, (void*)&partial,
                    (void*)&h1p, (void*)&h1, (void*)&outp};
    if (hipLaunchCooperativeKernel((void*)mega_kernel, dim3(GRID), dim3(256),
                                   args, 0, stream) == hipSuccess)
      return;
  }
  // Fallback: same phases as plain kernels (atomic-free, no memset needed).
  k_pool<<<GRID, 256, 0, stream>>>(x, lens, partial);
  k_segred<<<NSEQ, 256, 0, stream>>>(partial, lens, pooled);
  k_gemm1<<<48 * KS1, 256, 0, stream>>>(pooled, W1, h1p);
  k_redh1<<<NSEQ * FFD / 4 / 256, 256, 0, stream>>>(h1p, h1);
  k_gemm2<<<12 * KS2, 256, 0, stream>>>(h1, W2, outp);
  k_norm<<<NSEQ, 256, 0, stream>>>(outp, out);
}